// Round 1
// baseline (1429.765 us; speedup 1.0000x reference)
//
#include <hip/hip_runtime.h>

#define T 3
#define E 500000
#define F 128
#define H 64
#define B 1024

// ---- helpers ----------------------------------------------------------

// order-preserving float<->uint encoding for atomicMax on signed floats
__device__ __forceinline__ unsigned enc_f(float f) {
  unsigned u = __float_as_uint(f);
  return (u & 0x80000000u) ? ~u : (u | 0x80000000u);
}
__device__ __forceinline__ float dec_f(unsigned u) {
  return __uint_as_float((u & 0x80000000u) ? (u ^ 0x80000000u) : ~u);
}

__device__ __forceinline__ float tanh_fast(float x) {
  // tanh(x) = 1 - 2/(exp(2x)+1); robust at +-inf, ~1e-7 rel error
  float e = __expf(2.0f * x);
  return 1.0f - 2.0f / (e + 1.0f);
}

// ---- kernel 0: init + W1 transpose ------------------------------------

__global__ void k_init(const float* __restrict__ W1, float* __restrict__ W1T,
                       unsigned* __restrict__ smax, unsigned* __restrict__ cnt,
                       float* __restrict__ ssum) {
  int idx = blockIdx.x * blockDim.x + threadIdx.x;
  if (idx < T * B) {
    smax[idx] = 0u;   // enc of any real float is > 0
    cnt[idx] = 0u;
    ssum[idx] = 0.0f;
  }
  if (idx < T * H * F) {
    int t = idx / (H * F);
    int r = idx - t * (H * F);
    int j = r >> 7;          // H index
    int f = r & (F - 1);     // F index
    W1T[idx] = W1[(t * F + f) * H + j];
  }
}

// ---- kernel 1: per-edge MLP score + segment max + histogram -----------

__global__ __launch_bounds__(256) void k_score(
    const float* __restrict__ ea, const int* __restrict__ batch,
    const float* __restrict__ W1T, const float* __restrict__ b1,
    const float* __restrict__ W2, const float* __restrict__ b2,
    float* __restrict__ score, unsigned* __restrict__ smax,
    unsigned* __restrict__ cnt) {
  int t = blockIdx.y;
  int e = blockIdx.x * 256 + threadIdx.x;
  if (e >= E) return;

  // whole edge row in registers (statically indexed)
  const float4* row = (const float4*)(ea + ((size_t)t * E + e) * (size_t)F);
  float4 r[32];
#pragma unroll
  for (int i = 0; i < 32; ++i) r[i] = row[i];

  const float* w1t = W1T + t * H * F;
  const float* b1t = b1 + t * H;
  const float* w2t = W2 + t * H;

  float sc = b2[t];
  for (int j = 0; j < H; ++j) {     // uniform loop -> scalar weight loads
    const float* w = w1t + j * F;
    float a0 = 0.f, a1 = 0.f, a2 = 0.f, a3 = 0.f;
#pragma unroll
    for (int i = 0; i < 32; ++i) {
      a0 = fmaf(r[i].x, w[4 * i + 0], a0);
      a1 = fmaf(r[i].y, w[4 * i + 1], a1);
      a2 = fmaf(r[i].z, w[4 * i + 2], a2);
      a3 = fmaf(r[i].w, w[4 * i + 3], a3);
    }
    float h = tanh_fast(b1t[j] + (a0 + a1) + (a2 + a3));
    sc = fmaf(h, w2t[j], sc);
  }

  int b = batch[t * E + e];
  score[(size_t)t * E + e] = sc;
  atomicMax(&smax[t * B + b], enc_f(sc));
  atomicAdd(&cnt[t * B + b], 1u);
}

// ---- kernel 2: prefix sums (edge-list offsets) + smax decode ----------

__global__ void k_scan(const unsigned* __restrict__ cnt,
                       unsigned* __restrict__ offs,
                       unsigned* __restrict__ cursor,
                       unsigned* __restrict__ smax) {
  __shared__ unsigned s[B];
  int tid = threadIdx.x;
  for (int t = 0; t < T; ++t) {
    unsigned v = cnt[t * B + tid];
    s[tid] = v;
    __syncthreads();
    for (int d = 1; d < B; d <<= 1) {
      unsigned x = (tid >= d) ? s[tid - d] : 0u;
      __syncthreads();
      s[tid] += x;
      __syncthreads();
    }
    unsigned excl = s[tid] - v;   // exclusive scan
    offs[t * B + tid] = excl;
    cursor[t * B + tid] = excl;
    unsigned u = smax[t * B + tid];
    ((float*)smax)[t * B + tid] = dec_f(u);  // decode in place
    __syncthreads();
  }
}

// ---- kernel 3: exp + segment sum + counting-sort scatter --------------

__global__ __launch_bounds__(256) void k_bin(
    const int* __restrict__ batch, float* __restrict__ score_ex,
    const float* __restrict__ smax, float* __restrict__ ssum,
    unsigned* __restrict__ cursor, unsigned* __restrict__ eid) {
  int t = blockIdx.y;
  int e = blockIdx.x * 256 + threadIdx.x;
  if (e >= E) return;
  int b = batch[t * E + e];
  float sc = score_ex[(size_t)t * E + e];
  float ex = expf(sc - smax[t * B + b]);
  score_ex[(size_t)t * E + e] = ex;  // overwrite score with numerator
  atomicAdd(&ssum[t * B + b], ex);
  unsigned pos = atomicAdd(&cursor[t * B + b], 1u);
  eid[(size_t)t * E + pos] = e;
}

// ---- kernel 4: per-graph weighted gather-sum ---------------------------

__global__ __launch_bounds__(512) void k_pool(
    const float* __restrict__ ea, const float* __restrict__ exarr,
    const float* __restrict__ ssum, const unsigned* __restrict__ offs,
    const unsigned* __restrict__ cnt, const unsigned* __restrict__ eid,
    float* __restrict__ out) {
  int b = blockIdx.x;
  int f = threadIdx.x & (F - 1);
  int g = threadIdx.x >> 7;  // 4 edge groups

  float total = 0.0f;
  for (int t = 0; t < T; ++t) {
    unsigned c = cnt[t * B + b];
    if (c == 0u) continue;
    unsigned o = offs[t * B + b];
    const unsigned* ids = eid + (size_t)t * E + o;
    const float* exs = exarr + (size_t)t * E;
    const float* eat = ea + (size_t)t * E * (size_t)F;
    float part = 0.0f;
#pragma unroll 2
    for (unsigned i = g; i < c; i += 4) {
      unsigned id = ids[i];
      part = fmaf(exs[id], eat[(size_t)id * F + f], part);
    }
    float scale = (1.0f / 3.0f) / ssum[t * B + b];
    total = fmaf(part, scale, total);
  }

  __shared__ float red[512];
  red[threadIdx.x] = total;
  __syncthreads();
  if (g == 0)
    out[(size_t)b * F + f] =
        (red[f] + red[128 + f]) + (red[256 + f] + red[384 + f]);
}

// ---- launch ------------------------------------------------------------

extern "C" void kernel_launch(void* const* d_in, const int* in_sizes, int n_in,
                              void* d_out, int out_size, void* d_ws, size_t ws_size,
                              hipStream_t stream) {
  const float* ea    = (const float*)d_in[0];
  const int*   batch = (const int*)d_in[1];
  const float* W1    = (const float*)d_in[2];
  const float* b1    = (const float*)d_in[3];
  const float* W2    = (const float*)d_in[4];
  const float* b2    = (const float*)d_in[5];
  float* out = (float*)d_out;

  // workspace layout (~12.2 MB)
  float*    score_ex = (float*)d_ws;                       // T*E f32
  unsigned* eid      = (unsigned*)(score_ex + (size_t)T * E); // T*E u32
  float*    W1T      = (float*)(eid + (size_t)T * E);      // T*H*F f32
  unsigned* smax     = (unsigned*)(W1T + T * H * F);       // T*B (enc -> f32)
  unsigned* cnt      = smax + T * B;                       // T*B u32
  unsigned* offs     = cnt + T * B;                        // T*B u32
  unsigned* cursor   = offs + T * B;                       // T*B u32
  float*    ssum     = (float*)(cursor + T * B);           // T*B f32

  k_init<<<dim3((T * H * F + 255) / 256), 256, 0, stream>>>(W1, W1T, smax, cnt, ssum);

  dim3 ge((E + 255) / 256, T);
  k_score<<<ge, 256, 0, stream>>>(ea, batch, W1T, b1, W2, b2, score_ex, smax, cnt);
  k_scan<<<1, B, 0, stream>>>(cnt, offs, cursor, smax);
  k_bin<<<ge, 256, 0, stream>>>(batch, score_ex, (const float*)smax, ssum, cursor, eid);
  k_pool<<<B, 512, 0, stream>>>(ea, score_ex, ssum, offs, cnt, eid, out);
}

// Round 2
// 1346.825 us; speedup vs baseline: 1.0616x; 1.0616x over previous
//
#include <hip/hip_runtime.h>

#define T 3
#define E 500000
#define F 128
#define H 64
#define B 1024

// ---- helpers ----------------------------------------------------------

__device__ __forceinline__ float tanh_fast(float x) {
  // tanh(x) = 1 - 2/(exp(2x)+1); robust at +-inf
  float e = __expf(2.0f * x);
  return 1.0f - 2.0f / (e + 1.0f);
}

// ---- kernel 0: init + W1 transpose ------------------------------------

__global__ void k_init(const float* __restrict__ W1, float* __restrict__ W1T,
                       unsigned* __restrict__ cnt, float* __restrict__ ssum) {
  int idx = blockIdx.x * blockDim.x + threadIdx.x;
  if (idx < T * B) {
    cnt[idx] = 0u;
    ssum[idx] = 0.0f;
  }
  if (idx < T * H * F) {
    int t = idx / (H * F);
    int r = idx - t * (H * F);
    int j = r >> 7;          // H index
    int f = r & (F - 1);     // F index
    W1T[idx] = W1[(t * F + f) * H + j];
  }
}

// ---- kernel 1: per-edge MLP -> ex = exp(score); segment sum + hist ----
// No max-subtraction: |score| <= ||W2||_1 ~ 6, exp() cannot overflow, and
// attn = ex/ssum has identical relative rounding either way.

__global__ __launch_bounds__(256, 2) void k_score(
    const float* __restrict__ ea, const int* __restrict__ batch,
    const float* __restrict__ W1T, const float* __restrict__ b1,
    const float* __restrict__ W2, const float* __restrict__ b2,
    float* __restrict__ exarr, float* __restrict__ ssum,
    unsigned* __restrict__ cnt) {
  int t = blockIdx.y;
  int e = blockIdx.x * 256 + threadIdx.x;
  if (e >= E) return;

  // whole edge row register-resident (128 VGPRs, statically indexed)
  const float4* row = (const float4*)(ea + ((size_t)t * E + e) * (size_t)F);
  float4 r[32];
#pragma unroll
  for (int i = 0; i < 32; ++i) r[i] = row[i];

  const float* w1t = W1T + t * H * F;
  const float* b1t = b1 + t * H;
  const float* w2t = W2 + t * H;

  float sc = b2[t];
  for (int j = 0; j < H; ++j) {   // wave-uniform weights -> s_load + v_fmac(v,s)
    const float* w = w1t + j * F;
    float a0 = 0.f, a1 = 0.f, a2 = 0.f, a3 = 0.f;
#pragma unroll
    for (int i = 0; i < 32; ++i) {
      a0 = fmaf(r[i].x, w[4 * i + 0], a0);
      a1 = fmaf(r[i].y, w[4 * i + 1], a1);
      a2 = fmaf(r[i].z, w[4 * i + 2], a2);
      a3 = fmaf(r[i].w, w[4 * i + 3], a3);
    }
    float h = tanh_fast(b1t[j] + (a0 + a1) + (a2 + a3));
    sc = fmaf(h, w2t[j], sc);
  }

  float ex = __expf(sc);
  int b = batch[t * E + e];
  exarr[(size_t)t * E + e] = ex;
  atomicAdd(&ssum[t * B + b], ex);
  atomicAdd(&cnt[t * B + b], 1u);
}

// ---- kernel 2: prefix sums (edge-list offsets) ------------------------

__global__ void k_scan(const unsigned* __restrict__ cnt,
                       unsigned* __restrict__ offs,
                       unsigned* __restrict__ cursor) {
  __shared__ unsigned s[B];
  int tid = threadIdx.x;
  for (int t = 0; t < T; ++t) {
    unsigned v = cnt[t * B + tid];
    s[tid] = v;
    __syncthreads();
    for (int d = 1; d < B; d <<= 1) {
      unsigned x = (tid >= d) ? s[tid - d] : 0u;
      __syncthreads();
      s[tid] += x;
      __syncthreads();
    }
    unsigned excl = s[tid] - v;   // exclusive scan
    offs[t * B + tid] = excl;
    cursor[t * B + tid] = excl;
    __syncthreads();
  }
}

// ---- kernel 3: counting-sort scatter of edge ids ----------------------

__global__ __launch_bounds__(256) void k_scatter(
    const int* __restrict__ batch, unsigned* __restrict__ cursor,
    unsigned* __restrict__ eid) {
  int t = blockIdx.y;
  int e = blockIdx.x * 256 + threadIdx.x;
  if (e >= E) return;
  int b = batch[t * E + e];
  unsigned pos = atomicAdd(&cursor[t * B + b], 1u);
  eid[(size_t)t * E + pos] = e;
}

// ---- kernel 4: per-graph weighted gather-sum (float4) -----------------

__global__ __launch_bounds__(512) void k_pool(
    const float* __restrict__ ea, const float* __restrict__ exarr,
    const float* __restrict__ ssum, const unsigned* __restrict__ offs,
    const unsigned* __restrict__ cnt, const unsigned* __restrict__ eid,
    float* __restrict__ out) {
  int b = blockIdx.x;
  int f4 = threadIdx.x & 31;   // float4 index within row (32 x 16B = 512B)
  int g = threadIdx.x >> 5;    // 16 edge groups

  float4 total = {0.f, 0.f, 0.f, 0.f};
  for (int t = 0; t < T; ++t) {
    unsigned c = cnt[t * B + b];
    if (c == 0u) continue;
    unsigned o = offs[t * B + b];
    const unsigned* ids = eid + (size_t)t * E + o;
    const float* exs = exarr + (size_t)t * E;
    const float4* eat = (const float4*)(ea + (size_t)t * E * (size_t)F);
    float4 part = {0.f, 0.f, 0.f, 0.f};
    for (unsigned i = g; i < c; i += 16) {
      unsigned id = ids[i];                 // uniform across 32-lane group
      float w = exs[id];
      float4 v = eat[(size_t)id * 32 + f4]; // 32 lanes x 16B = full row
      part.x = fmaf(w, v.x, part.x);
      part.y = fmaf(w, v.y, part.y);
      part.z = fmaf(w, v.z, part.z);
      part.w = fmaf(w, v.w, part.w);
    }
    float scale = (1.0f / 3.0f) / ssum[t * B + b];
    total.x = fmaf(part.x, scale, total.x);
    total.y = fmaf(part.y, scale, total.y);
    total.z = fmaf(part.z, scale, total.z);
    total.w = fmaf(part.w, scale, total.w);
  }

  __shared__ float4 red[512];
  red[threadIdx.x] = total;
  __syncthreads();
  if (threadIdx.x < 32) {
    float4 acc = red[threadIdx.x];
#pragma unroll
    for (int gg = 1; gg < 16; ++gg) {
      float4 v = red[gg * 32 + threadIdx.x];
      acc.x += v.x; acc.y += v.y; acc.z += v.z; acc.w += v.w;
    }
    ((float4*)out)[(size_t)b * 32 + threadIdx.x] = acc;
  }
}

// ---- launch ------------------------------------------------------------

extern "C" void kernel_launch(void* const* d_in, const int* in_sizes, int n_in,
                              void* d_out, int out_size, void* d_ws, size_t ws_size,
                              hipStream_t stream) {
  const float* ea    = (const float*)d_in[0];
  const int*   batch = (const int*)d_in[1];
  const float* W1    = (const float*)d_in[2];
  const float* b1    = (const float*)d_in[3];
  const float* W2    = (const float*)d_in[4];
  const float* b2    = (const float*)d_in[5];
  float* out = (float*)d_out;

  // workspace layout (~12.2 MB)
  float*    exarr  = (float*)d_ws;                          // T*E f32
  unsigned* eid    = (unsigned*)(exarr + (size_t)T * E);    // T*E u32
  float*    W1T    = (float*)(eid + (size_t)T * E);         // T*H*F f32
  unsigned* cnt    = (unsigned*)(W1T + T * H * F);          // T*B u32
  unsigned* offs   = cnt + T * B;                           // T*B u32
  unsigned* cursor = offs + T * B;                          // T*B u32
  float*    ssum   = (float*)(cursor + T * B);              // T*B f32

  k_init<<<dim3((T * H * F + 255) / 256), 256, 0, stream>>>(W1, W1T, cnt, ssum);

  dim3 ge((E + 255) / 256, T);
  k_score<<<ge, 256, 0, stream>>>(ea, batch, W1T, b1, W2, b2, exarr, ssum, cnt);
  k_scan<<<1, B, 0, stream>>>(cnt, offs, cursor);
  k_scatter<<<ge, 256, 0, stream>>>(batch, cursor, eid);
  k_pool<<<B, 512, 0, stream>>>(ea, exarr, ssum, offs, cnt, eid, out);
}

// Round 3
// 1080.307 us; speedup vs baseline: 1.3235x; 1.2467x over previous
//
#include <hip/hip_runtime.h>

#define T 3
#define E 500000
#define F 128
#define H 64
#define B 1024

// ---- helpers ----------------------------------------------------------

__device__ __forceinline__ float tanh_fast(float x) {
  // tanh(x) = 1 - 2/(exp(2x)+1); robust at +-inf
  float e = __expf(2.0f * x);
  return 1.0f - 2.0f / (e + 1.0f);
}

// ---- kernel 0: init ----------------------------------------------------

__global__ void k_init(unsigned* __restrict__ cnt, float* __restrict__ ssum) {
  int idx = blockIdx.x * blockDim.x + threadIdx.x;
  if (idx < T * B) {
    cnt[idx] = 0u;
    ssum[idx] = 0.0f;
  }
}

// ---- kernel 1: per-edge MLP -> ex = exp(score); segment sum + hist ----
// f-outer / j-inner: 64 accumulators live (statically indexed), row chunk
// of 4 floats live briefly; weights are wave-uniform contiguous 64-float
// blocks of W1 -> scalar loads. No max-subtraction: |score| <= ||W2||_1 ~ 6,
// exp() cannot overflow; attn = ex/ssum rounding is unchanged.

__global__ __launch_bounds__(256, 4) void k_score(
    const float* __restrict__ ea, const int* __restrict__ batch,
    const float* __restrict__ W1, const float* __restrict__ b1,
    const float* __restrict__ W2, const float* __restrict__ b2,
    float* __restrict__ exarr, float* __restrict__ ssum,
    unsigned* __restrict__ cnt) {
  int t = blockIdx.y;
  int e = blockIdx.x * 256 + threadIdx.x;
  if (e >= E) return;

  const float4* row = (const float4*)(ea + ((size_t)t * E + e) * (size_t)F);
  const float* w1 = W1 + (size_t)t * F * H;   // [F][H] row-major, per type

  float acc[H];
#pragma unroll
  for (int j = 0; j < H; ++j) acc[j] = 0.0f;

#pragma unroll 2
  for (int i = 0; i < F / 4; ++i) {
    float4 rv = row[i];
    const float* w = w1 + (4 * i) * H;  // 4 consecutive weight rows (uniform)
#pragma unroll
    for (int j = 0; j < H; ++j) acc[j] = fmaf(rv.x, w[j], acc[j]);
#pragma unroll
    for (int j = 0; j < H; ++j) acc[j] = fmaf(rv.y, w[H + j], acc[j]);
#pragma unroll
    for (int j = 0; j < H; ++j) acc[j] = fmaf(rv.z, w[2 * H + j], acc[j]);
#pragma unroll
    for (int j = 0; j < H; ++j) acc[j] = fmaf(rv.w, w[3 * H + j], acc[j]);
  }

  const float* b1t = b1 + t * H;
  const float* w2t = W2 + t * H;
  float sc = b2[t];
#pragma unroll
  for (int j = 0; j < H; ++j) {
    float h = tanh_fast(acc[j] + b1t[j]);
    sc = fmaf(h, w2t[j], sc);
  }

  float ex = __expf(sc);
  int b = batch[t * E + e];
  exarr[(size_t)t * E + e] = ex;
  atomicAdd(&ssum[t * B + b], ex);
  atomicAdd(&cnt[t * B + b], 1u);
}

// ---- kernel 2: prefix sums (edge-list offsets) ------------------------

__global__ void k_scan(const unsigned* __restrict__ cnt,
                       unsigned* __restrict__ offs,
                       unsigned* __restrict__ cursor) {
  __shared__ unsigned s[B];
  int tid = threadIdx.x;
  for (int t = 0; t < T; ++t) {
    unsigned v = cnt[t * B + tid];
    s[tid] = v;
    __syncthreads();
    for (int d = 1; d < B; d <<= 1) {
      unsigned x = (tid >= d) ? s[tid - d] : 0u;
      __syncthreads();
      s[tid] += x;
      __syncthreads();
    }
    unsigned excl = s[tid] - v;   // exclusive scan
    offs[t * B + tid] = excl;
    cursor[t * B + tid] = excl;
    __syncthreads();
  }
}

// ---- kernel 3: counting-sort scatter of edge ids ----------------------

__global__ __launch_bounds__(256) void k_scatter(
    const int* __restrict__ batch, unsigned* __restrict__ cursor,
    unsigned* __restrict__ eid) {
  int t = blockIdx.y;
  int e = blockIdx.x * 256 + threadIdx.x;
  if (e >= E) return;
  int b = batch[t * E + e];
  unsigned pos = atomicAdd(&cursor[t * B + b], 1u);
  eid[(size_t)t * E + pos] = e;
}

// ---- kernel 4: per-graph weighted gather-sum (float4) -----------------

__global__ __launch_bounds__(512) void k_pool(
    const float* __restrict__ ea, const float* __restrict__ exarr,
    const float* __restrict__ ssum, const unsigned* __restrict__ offs,
    const unsigned* __restrict__ cnt, const unsigned* __restrict__ eid,
    float* __restrict__ out) {
  int b = blockIdx.x;
  int f4 = threadIdx.x & 31;   // float4 index within row (32 x 16B = 512B)
  int g = threadIdx.x >> 5;    // 16 edge groups

  float4 total = {0.f, 0.f, 0.f, 0.f};
  for (int t = 0; t < T; ++t) {
    unsigned c = cnt[t * B + b];
    if (c == 0u) continue;
    unsigned o = offs[t * B + b];
    const unsigned* ids = eid + (size_t)t * E + o;
    const float* exs = exarr + (size_t)t * E;
    const float4* eat = (const float4*)(ea + (size_t)t * E * (size_t)F);
    float4 part = {0.f, 0.f, 0.f, 0.f};
#pragma unroll 4
    for (unsigned i = g; i < c; i += 16) {
      unsigned id = ids[i];                 // shared across 32-lane group
      float w = exs[id];
      float4 v = eat[(size_t)id * 32 + f4]; // 32 lanes x 16B = full row
      part.x = fmaf(w, v.x, part.x);
      part.y = fmaf(w, v.y, part.y);
      part.z = fmaf(w, v.z, part.z);
      part.w = fmaf(w, v.w, part.w);
    }
    float scale = (1.0f / 3.0f) / ssum[t * B + b];
    total.x = fmaf(part.x, scale, total.x);
    total.y = fmaf(part.y, scale, total.y);
    total.z = fmaf(part.z, scale, total.z);
    total.w = fmaf(part.w, scale, total.w);
  }

  __shared__ float4 red[512];
  red[threadIdx.x] = total;
  __syncthreads();
  if (threadIdx.x < 32) {
    float4 acc = red[threadIdx.x];
#pragma unroll
    for (int gg = 1; gg < 16; ++gg) {
      float4 v = red[gg * 32 + threadIdx.x];
      acc.x += v.x; acc.y += v.y; acc.z += v.z; acc.w += v.w;
    }
    ((float4*)out)[(size_t)b * 32 + threadIdx.x] = acc;
  }
}

// ---- launch ------------------------------------------------------------

extern "C" void kernel_launch(void* const* d_in, const int* in_sizes, int n_in,
                              void* d_out, int out_size, void* d_ws, size_t ws_size,
                              hipStream_t stream) {
  const float* ea    = (const float*)d_in[0];
  const int*   batch = (const int*)d_in[1];
  const float* W1    = (const float*)d_in[2];
  const float* b1    = (const float*)d_in[3];
  const float* W2    = (const float*)d_in[4];
  const float* b2    = (const float*)d_in[5];
  float* out = (float*)d_out;

  // workspace layout (~12.1 MB)
  float*    exarr  = (float*)d_ws;                          // T*E f32
  unsigned* eid    = (unsigned*)(exarr + (size_t)T * E);    // T*E u32
  unsigned* cnt    = (unsigned*)(eid + (size_t)T * E);      // T*B u32
  unsigned* offs   = cnt + T * B;                           // T*B u32
  unsigned* cursor = offs + T * B;                          // T*B u32
  float*    ssum   = (float*)(cursor + T * B);              // T*B f32

  k_init<<<(T * B + 255) / 256, 256, 0, stream>>>(cnt, ssum);

  dim3 ge((E + 255) / 256, T);
  k_score<<<ge, 256, 0, stream>>>(ea, batch, W1, b1, W2, b2, exarr, ssum, cnt);
  k_scan<<<1, B, 0, stream>>>(cnt, offs, cursor);
  k_scatter<<<ge, 256, 0, stream>>>(batch, cursor, eid);
  k_pool<<<B, 512, 0, stream>>>(ea, exarr, ssum, offs, cnt, eid, out);
}